// Round 10
// baseline (201.448 us; speedup 1.0000x reference)
//
#include <hip/hip_runtime.h>
#include <hip/hip_bf16.h>
#include <math.h>

#define BB 8
#define CC 64
#define HH 128
#define WW 128
#define OO 64
#define HWHW (HH*WW)

typedef short bf16x8 __attribute__((ext_vector_type(8)));
typedef float f32x4 __attribute__((ext_vector_type(4)));
typedef unsigned short ushort_t;
typedef unsigned int uint32;

__device__ __forceinline__ float bflo(uint32 u) {
  return __builtin_bit_cast(float, u << 16);
}
__device__ __forceinline__ float bfhi(uint32 u) {
  return __builtin_bit_cast(float, u & 0xffff0000u);
}
__device__ __forceinline__ ushort_t f2bf(float f) {
  __hip_bfloat16 h = __float2bfloat16(f);
  return *(ushort_t*)&h;
}

// ---------------- Kernel 1: NCHW fp32 -> NHWC bf16 transpose of x ----------------
__global__ __launch_bounds__(256) void k_transpose(const float* __restrict__ x,
                                                   ushort_t* __restrict__ xt) {
  __shared__ float tile[64][65];
  int blk = blockIdx.x;            // 2048 blocks: 8 batches * 256 hw-chunks
  int b = blk >> 8;
  int hw0 = (blk & 255) << 6;      // 64 hw positions per block
  int lane = threadIdx.x & 63;
  int g = threadIdx.x >> 6;        // 0..3
  const float* xb = x + (size_t)b * CC * HWHW;
#pragma unroll
  for (int i = 0; i < 16; ++i) {
    int c = g + i * 4;
    tile[lane][c] = xb[c * HWHW + hw0 + lane];   // coalesced read along hw
  }
  __syncthreads();
  ushort_t* xtb = xt + (size_t)b * HWHW * 64;
#pragma unroll
  for (int j = 0; j < 16; ++j) {
    int hwl = g + j * 4;
    xtb[(size_t)(hw0 + hwl) * 64 + lane] = f2bf(tile[hwl][lane]);  // coalesced along c
  }
}

// ---------------- Kernel 2: weight prep ----------------
// wbf:  w_dcn [O][c*9+t] fp32 -> [O][t*64+c] bf16   (36864 elems)
// w_om: rows 0..17 = w_off, 18..26 = w_mask, 27..31 = 0; [32][t*64+c] bf16 (18432)
__global__ __launch_bounds__(256) void k_wcast(const float* __restrict__ w_dcn,
                                               const float* __restrict__ w_off,
                                               const float* __restrict__ w_mask,
                                               ushort_t* __restrict__ wbf,
                                               ushort_t* __restrict__ w_om) {
  int i = blockIdx.x * 256 + threadIdx.x;   // 216 blocks * 256 = 55296
  if (i < 36864) {
    int o = i / 576;
    int ck = i % 576;
    int c = ck / 9;
    int t = ck % 9;
    wbf[o * 576 + t * 64 + c] = f2bf(w_dcn[i]);
  } else {
    int j = i - 36864;          // 0..18431
    int o = j / 576;
    int r = j % 576;
    int t = r / 64;
    int c = r % 64;
    float v = 0.f;
    if (o < 18) v = w_off[o * 576 + c * 9 + t];
    else if (o < 27) v = w_mask[(o - 18) * 576 + c * 9 + t];
    w_om[j] = f2bf(v);
  }
}

// ---------------- Kernel 3: fused offset-conv + deformable conv ----------------
// Block = 256 thr (4 waves), 32 px (2 rows x 16 cols). NO halo staging: x is
// L2/L3-resident (FETCH ~10MB for 3 rounds) -> corners read direct from global,
// clamped addr + validity-zeroed weight = fully branchless.
// B: wave (pr,ot): offset/mask conv, A-frags direct from global (clamp+zero at
//    edges), 18 MFMA vs w_om -> offm[32][36] (+bias, sigmoid on mask rows).
// C1: 288 taps / 256 thr: per (px,tap) 4 corners {premult weight, global pos}.
// G: wave (pr,kh): uniform 9 steps, SW-pipelined: tap tables 2 ahead (3-slot
//    rotation), corner loads 1 ahead (2 buffers). 4 MFMA/step into acc[4].
// R: 2-way reduce (kh=1 -> LDS, kh=0 adds + stores). 3 barriers total.
// blockIdx & 7 = batch -> each XCD's L2 holds one batch's 2MB x slice.
#define TAPW_OFF 0        // [9][33] x 16B = 4752
#define TAPA_OFF 4752     // 4752
#define OFFM_OFF 9504     // [32][36] f32 = 4608
#define RED_OFF  14112    // [2][4][64] f32x4 = 8192
#define SM_TOTAL 22304
__global__ __launch_bounds__(256, 4) void k_deform(const ushort_t* __restrict__ xtbf,
                                                   const ushort_t* __restrict__ w_om,
                                                   const float* __restrict__ b_off,
                                                   const float* __restrict__ b_mask,
                                                   const ushort_t* __restrict__ wbf,
                                                   float* __restrict__ out) {
  __shared__ __align__(16) unsigned char smem[SM_TOTAL];
  float* offm = (float*)(smem + OFFM_OFF);        // [32][36]
  f32x4* red = (f32x4*)(smem + RED_OFF);          // [2][4][64]

  int bi = blockIdx.x;            // 4096 blocks
  int b = bi & 7;                 // batch == XCD (round-robin dispatch)
  int idx = bi >> 3;              // 0..511
  int y = (idx >> 3) * 2;         // pixel row pair
  int x0 = (idx & 7) * 16;        // 16 consecutive x
  int tid = threadIdx.x;
  int wave = tid >> 6;
  int lane = tid & 63;
  int mr = lane & 15;             // pixel col (A row) / o-row (B)
  int kg = lane >> 4;             // k-quad
  int pr = wave >> 1;             // pixel row 0/1
  const ushort_t* xbu = xtbf + (size_t)b * HWHW * 64;
  const char* xb8 = (const char*)xbu;

  // ---- Phase B: offset/mask conv (all 4 waves: (pr, ot)) ----
  {
    int ot = wave & 1;
    f32x4 cacc = {0.f, 0.f, 0.f, 0.f};
    const ushort_t* wrow = w_om + (size_t)(ot * 16 + mr) * 576 + kg * 8;
#pragma unroll
    for (int s = 0; s < 18; ++s) {
      int t = s >> 1, h = s & 1;
      int ky = t / 3, kx = t % 3;            // compile-time
      int yy = y + pr + ky - 1;
      int xxm = x0 + mr + kx - 1;
      int yc = min(max(yy, 0), HH - 1);
      int xc = min(max(xxm, 0), WW - 1);
      bool ok = ((unsigned)yy < (unsigned)HH) && ((unsigned)xxm < (unsigned)WW);
      uint4 d = *(const uint4*)(xb8 + ((size_t)(yc * WW + xc) << 7) + h * 64 + kg * 16);
      d.x = ok ? d.x : 0u; d.y = ok ? d.y : 0u;
      d.z = ok ? d.z : 0u; d.w = ok ? d.w : 0u;
      bf16x8 a = __builtin_bit_cast(bf16x8, d);
      bf16x8 bb = *(const bf16x8*)(wrow + s * 32);
      cacc = __builtin_amdgcn_mfma_f32_16x16x32_bf16(a, bb, cacc, 0, 0, 0);
    }
    int o = ot * 16 + mr;
    float bias = 0.f;
    if (o < 18) bias = b_off[o];
    else if (o < 27) bias = b_mask[o - 18];
    bool is_mask = (o >= 18) && (o < 27);
#pragma unroll
    for (int r = 0; r < 4; ++r) {
      float v = cacc[r] + bias;
      float sg = 1.f / (1.f + expf(-v));
      cacc[r] = is_mask ? sg : v;
    }
    *(f32x4*)&offm[o * 36 + pr * 16 + kg * 4] = cacc;   // px = pr*16 + kg*4 + r
  }
  __syncthreads();

  // ---- Phase C1: per-tap corner tables (288 taps over 256 threads) ----
#pragma unroll
  for (int pass = 0; pass < 2; ++pass) {
    int tau = tid + pass * 256;
    if (tau < 288) {
      int p = tau / 9;
      int k = tau - p * 9;
      float dy = offm[(2 * k) * 36 + p];
      float dx = offm[(2 * k + 1) * 36 + p];
      float m = offm[(18 + k) * 36 + p];
      int yy_o = y + (p >> 4);
      int xx_o = x0 + (p & 15);
      float py = (float)(yy_o + k / 3 - 1) + dy;
      float pxf = (float)(xx_o + k % 3 - 1) + dx;
      float fy = floorf(py), fx = floorf(pxf);
      int y0i = (int)fy, x0i = (int)fx;
      float wy1 = py - fy, wx1 = pxf - fx;
      float wyv[2] = {1.f - wy1, wy1};
      float wxv[2] = {1.f - wx1, wx1};
      uint32 wq[4], aq[4];
#pragma unroll
      for (int ry = 0; ry < 2; ++ry) {
#pragma unroll
        for (int rx = 0; rx < 2; ++rx) {
          int yiq = y0i + ry;
          int xiq = x0i + rx;
          float valid = (((unsigned)yiq < (unsigned)HH) &&
                         ((unsigned)xiq < (unsigned)WW)) ? 1.f : 0.f;
          int yc = min(max(yiq, 0), HH - 1);
          int xc = min(max(xiq, 0), WW - 1);
          int e = ry * 2 + rx;
          wq[e] = __builtin_bit_cast(uint32, wyv[ry] * wxv[rx] * valid * m);
          aq[e] = (uint32)(yc * WW + xc);        // clamped global position
        }
      }
      *(uint4*)(smem + TAPW_OFF + (k * 33 + p) * 16) = make_uint4(wq[0], wq[1], wq[2], wq[3]);
      *(uint4*)(smem + TAPA_OFF + (k * 33 + p) * 16) = make_uint4(aq[0], aq[1], aq[2], aq[3]);
    }
  }
  __syncthreads();

  // ---- Phase G: uniform 9-step gather + MFMA, SW-pipelined ----
  f32x4 acc0 = {0.f, 0.f, 0.f, 0.f}, acc1 = acc0, acc2 = acc0, acc3 = acc0;
  {
    int kh = wave & 1;
    int px = pr * 16 + mr;
    int cb = kh * 64 + kg * 16;                  // this lane's 8-channel bytes
    const ushort_t* wbase = wbf + (size_t)mr * 576 + kh * 32 + kg * 8;

    uint4 wqA, aqA, wqB, aqB, wqC, aqC;
    uint4 dA_0, dA_1, dA_2, dA_3, dB_0, dB_1, dB_2, dB_3;

#define LD_TW(I) (*(const uint4*)(smem + TAPW_OFF + ((I) * 33 + px) * 16))
#define LD_TA(I) (*(const uint4*)(smem + TAPA_OFF + ((I) * 33 + px) * 16))
#define TLOAD(S, I) { wq##S = LD_TW(I); aq##S = LD_TA(I); }
#define CLOAD(BUF, S) {                                                       \
    d##BUF##_0 = *(const uint4*)(xb8 + ((size_t)aq##S.x << 7) + cb);          \
    d##BUF##_1 = *(const uint4*)(xb8 + ((size_t)aq##S.y << 7) + cb);          \
    d##BUF##_2 = *(const uint4*)(xb8 + ((size_t)aq##S.z << 7) + cb);          \
    d##BUF##_3 = *(const uint4*)(xb8 + ((size_t)aq##S.w << 7) + cb); }
#define GSTEP(S, BUF, T) {                                                    \
    float fw0 = __builtin_bit_cast(float, wq##S.x);                           \
    float fw1 = __builtin_bit_cast(float, wq##S.y);                           \
    float fw2 = __builtin_bit_cast(float, wq##S.z);                           \
    float fw3 = __builtin_bit_cast(float, wq##S.w);                           \
    float s0 = fw0 * bflo(d##BUF##_0.x), s1 = fw0 * bfhi(d##BUF##_0.x);       \
    float s2 = fw0 * bflo(d##BUF##_0.y), s3 = fw0 * bfhi(d##BUF##_0.y);       \
    float s4 = fw0 * bflo(d##BUF##_0.z), s5 = fw0 * bfhi(d##BUF##_0.z);       \
    float s6 = fw0 * bflo(d##BUF##_0.w), s7 = fw0 * bfhi(d##BUF##_0.w);       \
    s0 += fw1 * bflo(d##BUF##_1.x); s1 += fw1 * bfhi(d##BUF##_1.x);           \
    s2 += fw1 * bflo(d##BUF##_1.y); s3 += fw1 * bfhi(d##BUF##_1.y);           \
    s4 += fw1 * bflo(d##BUF##_1.z); s5 += fw1 * bfhi(d##BUF##_1.z);           \
    s6 += fw1 * bflo(d##BUF##_1.w); s7 += fw1 * bfhi(d##BUF##_1.w);           \
    s0 += fw2 * bflo(d##BUF##_2.x); s1 += fw2 * bfhi(d##BUF##_2.x);           \
    s2 += fw2 * bflo(d##BUF##_2.y); s3 += fw2 * bfhi(d##BUF##_2.y);           \
    s4 += fw2 * bflo(d##BUF##_2.z); s5 += fw2 * bfhi(d##BUF##_2.z);           \
    s6 += fw2 * bflo(d##BUF##_2.w); s7 += fw2 * bfhi(d##BUF##_2.w);           \
    s0 += fw3 * bflo(d##BUF##_3.x); s1 += fw3 * bfhi(d##BUF##_3.x);           \
    s2 += fw3 * bflo(d##BUF##_3.y); s3 += fw3 * bfhi(d##BUF##_3.y);           \
    s4 += fw3 * bflo(d##BUF##_3.z); s5 += fw3 * bfhi(d##BUF##_3.z);           \
    s6 += fw3 * bflo(d##BUF##_3.w); s7 += fw3 * bfhi(d##BUF##_3.w);           \
    uint32 p0 = __builtin_amdgcn_perm(__builtin_bit_cast(uint32, s1) + 0x8000u, \
                                      __builtin_bit_cast(uint32, s0) + 0x8000u, \
                                      0x07060302u);                           \
    uint32 p1 = __builtin_amdgcn_perm(__builtin_bit_cast(uint32, s3) + 0x8000u, \
                                      __builtin_bit_cast(uint32, s2) + 0x8000u, \
                                      0x07060302u);                           \
    uint32 p2 = __builtin_amdgcn_perm(__builtin_bit_cast(uint32, s5) + 0x8000u, \
                                      __builtin_bit_cast(uint32, s4) + 0x8000u, \
                                      0x07060302u);                           \
    uint32 p3 = __builtin_amdgcn_perm(__builtin_bit_cast(uint32, s7) + 0x8000u, \
                                      __builtin_bit_cast(uint32, s6) + 0x8000u, \
                                      0x07060302u);                           \
    bf16x8 afrag = __builtin_bit_cast(bf16x8, make_uint4(p0, p1, p2, p3));    \
    const ushort_t* wp = wbase + (T) * 64;                                    \
    acc0 = __builtin_amdgcn_mfma_f32_16x16x32_bf16(afrag, *(const bf16x8*)(wp), acc0, 0, 0, 0); \
    acc1 = __builtin_amdgcn_mfma_f32_16x16x32_bf16(afrag, *(const bf16x8*)(wp + 9216), acc1, 0, 0, 0); \
    acc2 = __builtin_amdgcn_mfma_f32_16x16x32_bf16(afrag, *(const bf16x8*)(wp + 18432), acc2, 0, 0, 0); \
    acc3 = __builtin_amdgcn_mfma_f32_16x16x32_bf16(afrag, *(const bf16x8*)(wp + 27648), acc3, 0, 0, 0); }

    TLOAD(A, 0) TLOAD(B, 1) CLOAD(A, A)
    TLOAD(C, 2) CLOAD(B, B) GSTEP(A, A, 0)
    TLOAD(A, 3) CLOAD(A, C) GSTEP(B, B, 1)
    TLOAD(B, 4) CLOAD(B, A) GSTEP(C, A, 2)
    TLOAD(C, 5) CLOAD(A, B) GSTEP(A, B, 3)
    TLOAD(A, 6) CLOAD(B, C) GSTEP(B, A, 4)
    TLOAD(B, 7) CLOAD(A, A) GSTEP(C, B, 5)
    TLOAD(C, 8) CLOAD(B, B) GSTEP(A, A, 6)
                CLOAD(A, C) GSTEP(B, B, 7)
                            GSTEP(C, A, 8)
#undef LD_TW
#undef LD_TA
#undef TLOAD
#undef CLOAD
#undef GSTEP
  }

  // ---- Phase R: 2-way reduce (kh pairs), kh=0 stores ----
  {
    int kh = wave & 1;
    if (kh == 1) {
      red[(pr * 4 + 0) * 64 + lane] = acc0;
      red[(pr * 4 + 1) * 64 + lane] = acc1;
      red[(pr * 4 + 2) * 64 + lane] = acc2;
      red[(pr * 4 + 3) * 64 + lane] = acc3;
    }
    __syncthreads();
    if (kh == 0) {
      f32x4 v0 = acc0 + red[(pr * 4 + 0) * 64 + lane];
      f32x4 v1 = acc1 + red[(pr * 4 + 1) * 64 + lane];
      f32x4 v2 = acc2 + red[(pr * 4 + 2) * 64 + lane];
      f32x4 v3 = acc3 + red[(pr * 4 + 3) * 64 + lane];
      size_t rowoff = (size_t)(y + pr) * WW + x0 + kg * 4;
      float* o0 = out + (size_t)(b * 64 + 0 * 16 + mr) * HWHW + rowoff;
      float* o1 = out + (size_t)(b * 64 + 1 * 16 + mr) * HWHW + rowoff;
      float* o2 = out + (size_t)(b * 64 + 2 * 16 + mr) * HWHW + rowoff;
      float* o3 = out + (size_t)(b * 64 + 3 * 16 + mr) * HWHW + rowoff;
      *(f32x4*)o0 = v0;
      *(f32x4*)o1 = v1;
      *(f32x4*)o2 = v2;
      *(f32x4*)o3 = v3;
    }
  }
}

extern "C" void kernel_launch(void* const* d_in, const int* in_sizes, int n_in,
                              void* d_out, int out_size, void* d_ws, size_t ws_size,
                              hipStream_t stream) {
  const float* x = (const float*)d_in[0];
  const float* w_off = (const float*)d_in[1];
  const float* b_off = (const float*)d_in[2];
  const float* w_mask = (const float*)d_in[3];
  const float* b_mask = (const float*)d_in[4];
  const float* w_dcn = (const float*)d_in[5];
  float* out = (float*)d_out;

  char* ws = (char*)d_ws;
  ushort_t* xtbf = (ushort_t*)ws;                         // 16,777,216 B
  ushort_t* wbf = (ushort_t*)(ws + 16777216);             //     73,728 B
  ushort_t* w_om = (ushort_t*)(ws + 16777216 + 73728);    //     36,864 B

  hipLaunchKernelGGL(k_transpose, dim3(2048), dim3(256), 0, stream, x, xtbf);
  hipLaunchKernelGGL(k_wcast, dim3(216), dim3(256), 0, stream, w_dcn, w_off, w_mask,
                     wbf, w_om);
  hipLaunchKernelGGL(k_deform, dim3(4096), dim3(256), 0, stream, xtbf, w_om,
                     b_off, b_mask, wbf, out);
}

// Round 11
// 131.247 us; speedup vs baseline: 1.5349x; 1.5349x over previous
//
#include <hip/hip_runtime.h>
#include <hip/hip_bf16.h>
#include <math.h>

#define BB 8
#define CC 64
#define HH 128
#define WW 128
#define OO 64
#define HWHW (HH*WW)

typedef short bf16x8 __attribute__((ext_vector_type(8)));
typedef float f32x4 __attribute__((ext_vector_type(4)));
typedef unsigned short ushort_t;
typedef unsigned int uint32;

__device__ __forceinline__ float bflo(uint32 u) {
  return __builtin_bit_cast(float, u << 16);
}
__device__ __forceinline__ float bfhi(uint32 u) {
  return __builtin_bit_cast(float, u & 0xffff0000u);
}
__device__ __forceinline__ ushort_t f2bf(float f) {
  __hip_bfloat16 h = __float2bfloat16(f);
  return *(ushort_t*)&h;
}

// ---------------- Kernel 1: NCHW fp32 -> NHWC bf16 transpose of x ----------------
__global__ __launch_bounds__(256) void k_transpose(const float* __restrict__ x,
                                                   ushort_t* __restrict__ xt) {
  __shared__ float tile[64][65];
  int blk = blockIdx.x;            // 2048 blocks: 8 batches * 256 hw-chunks
  int b = blk >> 8;
  int hw0 = (blk & 255) << 6;      // 64 hw positions per block
  int lane = threadIdx.x & 63;
  int g = threadIdx.x >> 6;        // 0..3
  const float* xb = x + (size_t)b * CC * HWHW;
#pragma unroll
  for (int i = 0; i < 16; ++i) {
    int c = g + i * 4;
    tile[lane][c] = xb[c * HWHW + hw0 + lane];   // coalesced read along hw
  }
  __syncthreads();
  ushort_t* xtb = xt + (size_t)b * HWHW * 64;
#pragma unroll
  for (int j = 0; j < 16; ++j) {
    int hwl = g + j * 4;
    xtb[(size_t)(hw0 + hwl) * 64 + lane] = f2bf(tile[hwl][lane]);  // coalesced along c
  }
}

// ---------------- Kernel 2: weight prep ----------------
// wbf:  w_dcn [O][c*9+t] fp32 -> [O][t*64+c] bf16   (36864 elems)
// w_om: rows 0..17 = w_off, 18..26 = w_mask, 27..31 = 0; [32][t*64+c] bf16 (18432)
__global__ __launch_bounds__(256) void k_wcast(const float* __restrict__ w_dcn,
                                               const float* __restrict__ w_off,
                                               const float* __restrict__ w_mask,
                                               ushort_t* __restrict__ wbf,
                                               ushort_t* __restrict__ w_om) {
  int i = blockIdx.x * 256 + threadIdx.x;   // 216 blocks * 256 = 55296
  if (i < 36864) {
    int o = i / 576;
    int ck = i % 576;
    int c = ck / 9;
    int t = ck % 9;
    wbf[o * 576 + t * 64 + c] = f2bf(w_dcn[i]);
  } else {
    int j = i - 36864;          // 0..18431
    int o = j / 576;
    int r = j % 576;
    int t = r / 64;
    int c = r % 64;
    float v = 0.f;
    if (o < 18) v = w_off[o * 576 + c * 9 + t];
    else if (o < 27) v = w_mask[(o - 18) * 576 + c * 9 + t];
    w_om[j] = f2bf(v);
  }
}

// ---------------- Kernel 3: fused offset-conv + deformable conv ----------------
// Block = 256 thr (4 waves), 32 px (2 rows x 16 cols).
// A: stage halo [120 pos = 6r x 20c][144B] bf16, zero-filled OOB (covers conv
//    + bilinear reach; |offset| < 1 except ~3e-5 tail handled by fixup list).
// B: wave (pr,ot): offset/mask conv from halo, 18 MFMA -> offm (+bias/sigmoid).
// C1: 288 taps: 4 corners {premult weight, halo byte addr}. Out-of-halo corner
//    (rare): weight=0 in table + append {px,k,w,gpos} to LDS fixup list.
// G: wave (pr,kh): 9 uniform steps, ALL-LDS branch-free gather, explicit
//    3-table/2-buffer rotation (r10-proven); wave-uniform fbn check applies
//    exact corrections before bf16 pack; 4 MFMA/step.
// R: 2-way reduce (kh), red overlays dead halo; kh=0 stores NCHW float4.
// blockIdx&7 = batch -> per-XCD L2 locality.
#define HALO_OFF 0        // 120 * 144 = 17280
#define TAPW_OFF 17280    // [9][33] x 16B = 4752
#define TAPA_OFF 22032    // 4752
#define OFFM_OFF 26784    // [32][36] f32 = 4608
#define FB_OFF   31392    // cnt(16B-padded) + 16 entries x 16B = 272
#define RED_OFF  0        // overlay on halo (dead after G): [2][4][64] f32x4 = 8192
#define FB_MAX   16
#define SM_TOTAL 31680
__global__ __launch_bounds__(256, 5) void k_deform(const ushort_t* __restrict__ xtbf,
                                                   const ushort_t* __restrict__ w_om,
                                                   const float* __restrict__ b_off,
                                                   const float* __restrict__ b_mask,
                                                   const ushort_t* __restrict__ wbf,
                                                   float* __restrict__ out) {
  __shared__ __align__(16) unsigned char smem[SM_TOTAL];
  float* offm = (float*)(smem + OFFM_OFF);        // [32][36]
  f32x4* red = (f32x4*)(smem + RED_OFF);          // [2][4][64]

  int bi = blockIdx.x;            // 4096 blocks
  int b = bi & 7;                 // batch == XCD (round-robin dispatch)
  int idx = bi >> 3;              // 0..511
  int y = (idx >> 3) * 2;         // pixel row pair
  int x0 = (idx & 7) * 16;        // 16 consecutive x
  int tid = threadIdx.x;
  int wave = tid >> 6;
  int lane = tid & 63;
  int mr = lane & 15;             // pixel col (A row) / o-row (B)
  int kg = lane >> 4;             // k-quad
  int pr = wave >> 1;             // pixel row 0/1
  const ushort_t* xbu = xtbf + (size_t)b * HWHW * 64;
  const char* xb8 = (const char*)xbu;

  // ---- Phase A: stage 6x20 halo (16 thr/pos, 8B each) + init fixup count ----
  if (tid == 0) *(int*)(smem + FB_OFF) = 0;
  {
    int c8 = (tid & 15) * 8;     // byte offset of 4 channels
#pragma unroll
    for (int i = 0; i < 8; ++i) {
      int pos = (tid >> 4) + i * 16;
      if (pos < 120) {
        int r = pos / 20;
        int j = pos - r * 20;
        int yy = y - 2 + r;
        int xx = x0 - 2 + j;
        uint2 d = make_uint2(0u, 0u);
        if (((unsigned)yy < (unsigned)HH) && ((unsigned)xx < (unsigned)WW))
          d = *(const uint2*)(xb8 + ((size_t)(yy * WW + xx) << 7) + c8);
        *(uint2*)(smem + pos * 144 + c8) = d;
      }
    }
  }
  __syncthreads();

  // ---- Phase B: offset/mask conv from halo (all 4 waves: (pr, ot)) ----
  {
    int ot = wave & 1;
    f32x4 cacc = {0.f, 0.f, 0.f, 0.f};
    const ushort_t* wrow = w_om + (size_t)(ot * 16 + mr) * 576 + kg * 8;
#pragma unroll
    for (int s = 0; s < 18; ++s) {
      int t = s >> 1, h = s & 1;
      int ky = t / 3, kx = t % 3;            // compile-time
      int pos = (pr + ky + 1) * 20 + (mr + kx + 1);
      bf16x8 a = *(const bf16x8*)(smem + pos * 144 + h * 64 + kg * 16);
      bf16x8 bb = *(const bf16x8*)(wrow + s * 32);
      cacc = __builtin_amdgcn_mfma_f32_16x16x32_bf16(a, bb, cacc, 0, 0, 0);
    }
    int o = ot * 16 + mr;
    float bias = 0.f;
    if (o < 18) bias = b_off[o];
    else if (o < 27) bias = b_mask[o - 18];
    bool is_mask = (o >= 18) && (o < 27);
#pragma unroll
    for (int r = 0; r < 4; ++r) {
      float v = cacc[r] + bias;
      float sg = 1.f / (1.f + expf(-v));
      cacc[r] = is_mask ? sg : v;
    }
    *(f32x4*)&offm[o * 36 + pr * 16 + kg * 4] = cacc;   // px = pr*16 + kg*4 + r
  }
  __syncthreads();

  // ---- Phase C1: per-tap corner tables (288 taps over 256 threads) ----
#pragma unroll
  for (int pass = 0; pass < 2; ++pass) {
    int tau = tid + pass * 256;
    if (tau < 288) {
      int p = tau / 9;
      int k = tau - p * 9;
      float dy = offm[(2 * k) * 36 + p];
      float dx = offm[(2 * k + 1) * 36 + p];
      float m = offm[(18 + k) * 36 + p];
      int yy_o = y + (p >> 4);
      int xx_o = x0 + (p & 15);
      float py = (float)(yy_o + k / 3 - 1) + dy;
      float pxf = (float)(xx_o + k % 3 - 1) + dx;
      float fy = floorf(py), fx = floorf(pxf);
      int y0i = (int)fy, x0i = (int)fx;
      float wy1 = py - fy, wx1 = pxf - fx;
      float wyv[2] = {1.f - wy1, wy1};
      float wxv[2] = {1.f - wx1, wx1};
      uint32 wq[4], aq[4];
#pragma unroll
      for (int ry = 0; ry < 2; ++ry) {
#pragma unroll
        for (int rx = 0; rx < 2; ++rx) {
          int yiq = y0i + ry;
          int xiq = x0i + rx;
          float valid = (((unsigned)yiq < (unsigned)HH) &&
                         ((unsigned)xiq < (unsigned)WW)) ? 1.f : 0.f;
          int yc = min(max(yiq, 0), HH - 1);
          int xc = min(max(xiq, 0), WW - 1);
          int rr = yc - (y - 2);
          int jj = xc - (x0 - 2);
          float w = wyv[ry] * wxv[rx] * valid * m;
          int e = ry * 2 + rx;
          if ((unsigned)rr < 6u && (unsigned)jj < 20u) {
            aq[e] = (uint32)((rr * 20 + jj) * 144);
            wq[e] = __builtin_bit_cast(uint32, w);
          } else {
            // rare (~3e-5): zero weight in table, exact fixup via list
            int rrc = min(max(rr, 0), 5), jjc = min(max(jj, 0), 19);
            aq[e] = (uint32)((rrc * 20 + jjc) * 144);
            wq[e] = 0u;
            if (w != 0.f) {
              int slot = atomicAdd((int*)(smem + FB_OFF), 1);
              if (slot < FB_MAX) {
                *(uint4*)(smem + FB_OFF + 16 + slot * 16) =
                    make_uint4((uint32)p | ((uint32)k << 8),
                               (uint32)(yc * WW + xc),
                               __builtin_bit_cast(uint32, w), 0u);
              }
            }
          }
        }
      }
      *(uint4*)(smem + TAPW_OFF + (k * 33 + p) * 16) = make_uint4(wq[0], wq[1], wq[2], wq[3]);
      *(uint4*)(smem + TAPA_OFF + (k * 33 + p) * 16) = make_uint4(aq[0], aq[1], aq[2], aq[3]);
    }
  }
  __syncthreads();

  // ---- Phase G: uniform 9-step ALL-LDS gather + MFMA, SW-pipelined ----
  f32x4 acc0 = {0.f, 0.f, 0.f, 0.f}, acc1 = acc0, acc2 = acc0, acc3 = acc0;
  int fbn = min(*(const int*)(smem + FB_OFF), FB_MAX);
  fbn = __builtin_amdgcn_readfirstlane(fbn);
  {
    int kh = wave & 1;
    int px = pr * 16 + mr;
    int cb = kh * 64 + kg * 16;                  // this lane's 8-channel bytes
    const ushort_t* wbase = wbf + (size_t)mr * 576 + kh * 32 + kg * 8;

    uint4 wqA, aqA, wqB, aqB, wqC, aqC;
    uint4 dA_0, dA_1, dA_2, dA_3, dB_0, dB_1, dB_2, dB_3;

#define TLOADX(S, I) {                                                        \
    wq##S = *(const uint4*)(smem + TAPW_OFF + ((I) * 33 + px) * 16);          \
    aq##S = *(const uint4*)(smem + TAPA_OFF + ((I) * 33 + px) * 16); }
#define CLOADX(BUF, S) {                                                      \
    d##BUF##_0 = *(const uint4*)(smem + aq##S.x + cb);                        \
    d##BUF##_1 = *(const uint4*)(smem + aq##S.y + cb);                        \
    d##BUF##_2 = *(const uint4*)(smem + aq##S.z + cb);                        \
    d##BUF##_3 = *(const uint4*)(smem + aq##S.w + cb); }
#define GSTEPX(S, BUF, T) {                                                   \
    float fw0 = __builtin_bit_cast(float, wq##S.x);                           \
    float fw1 = __builtin_bit_cast(float, wq##S.y);                           \
    float fw2 = __builtin_bit_cast(float, wq##S.z);                           \
    float fw3 = __builtin_bit_cast(float, wq##S.w);                           \
    float s0 = fw0 * bflo(d##BUF##_0.x), s1 = fw0 * bfhi(d##BUF##_0.x);       \
    float s2 = fw0 * bflo(d##BUF##_0.y), s3 = fw0 * bfhi(d##BUF##_0.y);       \
    float s4 = fw0 * bflo(d##BUF##_0.z), s5 = fw0 * bfhi(d##BUF##_0.z);       \
    float s6 = fw0 * bflo(d##BUF##_0.w), s7 = fw0 * bfhi(d##BUF##_0.w);       \
    s0 += fw1 * bflo(d##BUF##_1.x); s1 += fw1 * bfhi(d##BUF##_1.x);           \
    s2 += fw1 * bflo(d##BUF##_1.y); s3 += fw1 * bfhi(d##BUF##_1.y);           \
    s4 += fw1 * bflo(d##BUF##_1.z); s5 += fw1 * bfhi(d##BUF##_1.z);           \
    s6 += fw1 * bflo(d##BUF##_1.w); s7 += fw1 * bfhi(d##BUF##_1.w);           \
    s0 += fw2 * bflo(d##BUF##_2.x); s1 += fw2 * bfhi(d##BUF##_2.x);           \
    s2 += fw2 * bflo(d##BUF##_2.y); s3 += fw2 * bfhi(d##BUF##_2.y);           \
    s4 += fw2 * bflo(d##BUF##_2.z); s5 += fw2 * bfhi(d##BUF##_2.z);           \
    s6 += fw2 * bflo(d##BUF##_2.w); s7 += fw2 * bfhi(d##BUF##_2.w);           \
    s0 += fw3 * bflo(d##BUF##_3.x); s1 += fw3 * bfhi(d##BUF##_3.x);           \
    s2 += fw3 * bflo(d##BUF##_3.y); s3 += fw3 * bfhi(d##BUF##_3.y);           \
    s4 += fw3 * bflo(d##BUF##_3.z); s5 += fw3 * bfhi(d##BUF##_3.z);           \
    s6 += fw3 * bflo(d##BUF##_3.w); s7 += fw3 * bfhi(d##BUF##_3.w);           \
    if (fbn) {  /* wave-uniform, ~never taken */                              \
      for (int e = 0; e < fbn; ++e) {                                         \
        uint4 ent = *(const uint4*)(smem + FB_OFF + 16 + e * 16);             \
        if ((int)(ent.x >> 8) == (T) && (int)(ent.x & 255u) == px) {          \
          uint4 d = *(const uint4*)(xb8 + ((size_t)ent.y << 7) + cb);         \
          float fw = __builtin_bit_cast(float, ent.z);                        \
          s0 += fw * bflo(d.x); s1 += fw * bfhi(d.x);                         \
          s2 += fw * bflo(d.y); s3 += fw * bfhi(d.y);                         \
          s4 += fw * bflo(d.z); s5 += fw * bfhi(d.z);                         \
          s6 += fw * bflo(d.w); s7 += fw * bfhi(d.w);                         \
        }                                                                     \
      }                                                                       \
    }                                                                         \
    uint32 p0 = __builtin_amdgcn_perm(__builtin_bit_cast(uint32, s1) + 0x8000u, \
                                      __builtin_bit_cast(uint32, s0) + 0x8000u, \
                                      0x07060302u);                           \
    uint32 p1 = __builtin_amdgcn_perm(__builtin_bit_cast(uint32, s3) + 0x8000u, \
                                      __builtin_bit_cast(uint32, s2) + 0x8000u, \
                                      0x07060302u);                           \
    uint32 p2 = __builtin_amdgcn_perm(__builtin_bit_cast(uint32, s5) + 0x8000u, \
                                      __builtin_bit_cast(uint32, s4) + 0x8000u, \
                                      0x07060302u);                           \
    uint32 p3 = __builtin_amdgcn_perm(__builtin_bit_cast(uint32, s7) + 0x8000u, \
                                      __builtin_bit_cast(uint32, s6) + 0x8000u, \
                                      0x07060302u);                           \
    bf16x8 afrag = __builtin_bit_cast(bf16x8, make_uint4(p0, p1, p2, p3));    \
    const ushort_t* wp = wbase + (T) * 64;                                    \
    acc0 = __builtin_amdgcn_mfma_f32_16x16x32_bf16(afrag, *(const bf16x8*)(wp), acc0, 0, 0, 0); \
    acc1 = __builtin_amdgcn_mfma_f32_16x16x32_bf16(afrag, *(const bf16x8*)(wp + 9216), acc1, 0, 0, 0); \
    acc2 = __builtin_amdgcn_mfma_f32_16x16x32_bf16(afrag, *(const bf16x8*)(wp + 18432), acc2, 0, 0, 0); \
    acc3 = __builtin_amdgcn_mfma_f32_16x16x32_bf16(afrag, *(const bf16x8*)(wp + 27648), acc3, 0, 0, 0); }

    TLOADX(A, 0) TLOADX(B, 1) CLOADX(A, A)
    TLOADX(C, 2) CLOADX(B, B) GSTEPX(A, A, 0)
    TLOADX(A, 3) CLOADX(A, C) GSTEPX(B, B, 1)
    TLOADX(B, 4) CLOADX(B, A) GSTEPX(C, A, 2)
    TLOADX(C, 5) CLOADX(A, B) GSTEPX(A, B, 3)
    TLOADX(A, 6) CLOADX(B, C) GSTEPX(B, A, 4)
    TLOADX(B, 7) CLOADX(A, A) GSTEPX(C, B, 5)
    TLOADX(C, 8) CLOADX(B, B) GSTEPX(A, A, 6)
                 CLOADX(A, C) GSTEPX(B, B, 7)
                              GSTEPX(C, A, 8)
#undef TLOADX
#undef CLOADX
#undef GSTEPX
  }

  // ---- Phase R: 2-way reduce (kh pairs) over dead halo; kh=0 stores ----
  __syncthreads();                 // all halo reads done before overlay
  {
    int kh = wave & 1;
    if (kh == 1) {
      red[(pr * 4 + 0) * 64 + lane] = acc0;
      red[(pr * 4 + 1) * 64 + lane] = acc1;
      red[(pr * 4 + 2) * 64 + lane] = acc2;
      red[(pr * 4 + 3) * 64 + lane] = acc3;
    }
    __syncthreads();
    if (kh == 0) {
      f32x4 v0 = acc0 + red[(pr * 4 + 0) * 64 + lane];
      f32x4 v1 = acc1 + red[(pr * 4 + 1) * 64 + lane];
      f32x4 v2 = acc2 + red[(pr * 4 + 2) * 64 + lane];
      f32x4 v3 = acc3 + red[(pr * 4 + 3) * 64 + lane];
      size_t rowoff = (size_t)(y + pr) * WW + x0 + kg * 4;
      *(f32x4*)(out + (size_t)(b * 64 + 0 * 16 + mr) * HWHW + rowoff) = v0;
      *(f32x4*)(out + (size_t)(b * 64 + 1 * 16 + mr) * HWHW + rowoff) = v1;
      *(f32x4*)(out + (size_t)(b * 64 + 2 * 16 + mr) * HWHW + rowoff) = v2;
      *(f32x4*)(out + (size_t)(b * 64 + 3 * 16 + mr) * HWHW + rowoff) = v3;
    }
  }
}

extern "C" void kernel_launch(void* const* d_in, const int* in_sizes, int n_in,
                              void* d_out, int out_size, void* d_ws, size_t ws_size,
                              hipStream_t stream) {
  const float* x = (const float*)d_in[0];
  const float* w_off = (const float*)d_in[1];
  const float* b_off = (const float*)d_in[2];
  const float* w_mask = (const float*)d_in[3];
  const float* b_mask = (const float*)d_in[4];
  const float* w_dcn = (const float*)d_in[5];
  float* out = (float*)d_out;

  char* ws = (char*)d_ws;
  ushort_t* xtbf = (ushort_t*)ws;                         // 16,777,216 B
  ushort_t* wbf = (ushort_t*)(ws + 16777216);             //     73,728 B
  ushort_t* w_om = (ushort_t*)(ws + 16777216 + 73728);    //     36,864 B

  hipLaunchKernelGGL(k_transpose, dim3(2048), dim3(256), 0, stream, x, xtbf);
  hipLaunchKernelGGL(k_wcast, dim3(216), dim3(256), 0, stream, w_dcn, w_off, w_mask,
                     wbf, w_om);
  hipLaunchKernelGGL(k_deform, dim3(4096), dim3(256), 0, stream, xtbf, w_om,
                     b_off, b_mask, wbf, out);
}

// Round 12
// 123.034 us; speedup vs baseline: 1.6373x; 1.0668x over previous
//
#include <hip/hip_runtime.h>
#include <hip/hip_bf16.h>
#include <math.h>

#define BB 8
#define CC 64
#define HH 128
#define WW 128
#define OO 64
#define HWHW (HH*WW)

typedef short bf16x8 __attribute__((ext_vector_type(8)));
typedef float f32x4 __attribute__((ext_vector_type(4)));
typedef unsigned short ushort_t;
typedef unsigned int uint32;

__device__ __forceinline__ float bflo(uint32 u) {
  return __builtin_bit_cast(float, u << 16);
}
__device__ __forceinline__ float bfhi(uint32 u) {
  return __builtin_bit_cast(float, u & 0xffff0000u);
}
__device__ __forceinline__ ushort_t f2bf(float f) {
  __hip_bfloat16 h = __float2bfloat16(f);
  return *(ushort_t*)&h;
}
// halo byte address for (clamped) halo coords; cb = lane channel-byte offset
__device__ __forceinline__ int haddr(int rr, int jj, int cb) {
  int rrc = min(max(rr, 0), 5);
  int jjc = min(max(jj, 0), 19);
  return rrc * 2880 + jjc * 144 + cb;
}
// weight: zero when raw coords outside halo (halo zeros handle image border)
__device__ __forceinline__ float hwt(int rr, int jj, float wb, float m) {
  bool inh = ((unsigned)rr < 6u) && ((unsigned)jj < 20u);
  return inh ? wb * m : 0.f;
}

// ---------------- Kernel 1: NCHW fp32 -> NHWC bf16 transpose of x ----------------
__global__ __launch_bounds__(256) void k_transpose(const float* __restrict__ x,
                                                   ushort_t* __restrict__ xt) {
  __shared__ float tile[64][65];
  int blk = blockIdx.x;            // 2048 blocks: 8 batches * 256 hw-chunks
  int b = blk >> 8;
  int hw0 = (blk & 255) << 6;      // 64 hw positions per block
  int lane = threadIdx.x & 63;
  int g = threadIdx.x >> 6;        // 0..3
  const float* xb = x + (size_t)b * CC * HWHW;
#pragma unroll
  for (int i = 0; i < 16; ++i) {
    int c = g + i * 4;
    tile[lane][c] = xb[c * HWHW + hw0 + lane];   // coalesced read along hw
  }
  __syncthreads();
  ushort_t* xtb = xt + (size_t)b * HWHW * 64;
#pragma unroll
  for (int j = 0; j < 16; ++j) {
    int hwl = g + j * 4;
    xtb[(size_t)(hw0 + hwl) * 64 + lane] = f2bf(tile[hwl][lane]);  // coalesced along c
  }
}

// ---------------- Kernel 2: weight prep ----------------
// wbf:  w_dcn [O][c*9+t] fp32 -> [O][t*64+c] bf16   (36864 elems)
// w_om: rows 0..17 = w_off, 18..26 = w_mask, 27..31 = 0; [32][t*64+c] bf16 (18432)
__global__ __launch_bounds__(256) void k_wcast(const float* __restrict__ w_dcn,
                                               const float* __restrict__ w_off,
                                               const float* __restrict__ w_mask,
                                               ushort_t* __restrict__ wbf,
                                               ushort_t* __restrict__ w_om) {
  int i = blockIdx.x * 256 + threadIdx.x;   // 216 blocks * 256 = 55296
  if (i < 36864) {
    int o = i / 576;
    int ck = i % 576;
    int c = ck / 9;
    int t = ck % 9;
    wbf[o * 576 + t * 64 + c] = f2bf(w_dcn[i]);
  } else {
    int j = i - 36864;          // 0..18431
    int o = j / 576;
    int r = j % 576;
    int t = r / 64;
    int c = r % 64;
    float v = 0.f;
    if (o < 18) v = w_off[o * 576 + c * 9 + t];
    else if (o < 27) v = w_mask[(o - 18) * 576 + c * 9 + t];
    w_om[j] = f2bf(v);
  }
}

// ---------------- Kernel 3: fused offset-conv + deformable conv ----------------
// Block = 256 thr (4 waves), 32 px (2 rows x 16 cols).
// A: stage halo [120 pos = 6r x 20c][144B] bf16, zero-filled OOB.
// B: wave (pr,ot): offset/mask conv from halo, 18 MFMA -> offm_t[px][44]
//    (TRANSPOSED: per-pixel row; +bias, sigmoid on mask channels).
// C1-lite: OOB-of-halo scan only -> rare fixup list (no tables).
// G: wave (pr,kh): lane loads its px's 27 offsets ONCE into 7 f32x4 regs;
//    per step: pure-VALU addr/weight math (compile-time indexed), 4 corner
//    ds_read_b128, 32 FMA, perm-pack, 4 MFMA. 2-buffer rotation; no
//    LDS-dependent addressing chain. Post-loop: rare exact fixup via MFMA.
// R: 2-way reduce (kh), red overlays dead halo; kh=0 stores NCHW float4.
// blockIdx&7 = batch -> per-XCD L2 locality.
#define HALO_OFF 0        // 120 * 144 = 17280
#define OFFT_OFF 17280    // offm_t[32][44] f32 = 5632
#define FB_OFF   22912    // cnt(16B) + 16 entries x 16B = 272
#define RED_OFF  0        // overlay on halo (dead after G): 8192 B
#define FB_MAX   16
#define SM_TOTAL 23184
__global__ __launch_bounds__(256, 4) void k_deform(const ushort_t* __restrict__ xtbf,
                                                   const ushort_t* __restrict__ w_om,
                                                   const float* __restrict__ b_off,
                                                   const float* __restrict__ b_mask,
                                                   const ushort_t* __restrict__ wbf,
                                                   float* __restrict__ out) {
  __shared__ __align__(16) unsigned char smem[SM_TOTAL];
  float* offt = (float*)(smem + OFFT_OFF);        // [32 px][44]
  f32x4* red = (f32x4*)(smem + RED_OFF);          // [2][4][64]

  int bi = blockIdx.x;            // 4096 blocks
  int b = bi & 7;                 // batch == XCD (round-robin dispatch)
  int idx = bi >> 3;              // 0..511
  int y = (idx >> 3) * 2;         // pixel row pair
  int x0 = (idx & 7) * 16;        // 16 consecutive x
  int tid = threadIdx.x;
  int wave = tid >> 6;
  int lane = tid & 63;
  int mr = lane & 15;             // pixel col (A row) / o-row (B)
  int kg = lane >> 4;             // k-quad
  int pr = wave >> 1;             // pixel row 0/1
  const ushort_t* xbu = xtbf + (size_t)b * HWHW * 64;
  const char* xb8 = (const char*)xbu;

  // ---- Phase A: stage 6x20 halo (16 thr/pos, 8B each) + init fixup count ----
  if (tid == 0) *(int*)(smem + FB_OFF) = 0;
  {
    int c8 = (tid & 15) * 8;     // byte offset of 4 channels
#pragma unroll
    for (int i = 0; i < 8; ++i) {
      int pos = (tid >> 4) + i * 16;
      if (pos < 120) {
        int r = pos / 20;
        int j = pos - r * 20;
        int yy = y - 2 + r;
        int xx = x0 - 2 + j;
        uint2 d = make_uint2(0u, 0u);
        if (((unsigned)yy < (unsigned)HH) && ((unsigned)xx < (unsigned)WW))
          d = *(const uint2*)(xb8 + ((size_t)(yy * WW + xx) << 7) + c8);
        *(uint2*)(smem + pos * 144 + c8) = d;
      }
    }
  }
  __syncthreads();

  // ---- Phase B: offset/mask conv from halo -> offm_t (all 4 waves) ----
  {
    int ot = wave & 1;
    f32x4 cacc = {0.f, 0.f, 0.f, 0.f};
    const ushort_t* wrow = w_om + (size_t)(ot * 16 + mr) * 576 + kg * 8;
#pragma unroll
    for (int s = 0; s < 18; ++s) {
      int t = s >> 1, h = s & 1;
      int ky = t / 3, kx = t % 3;            // compile-time
      int pos = (pr + ky + 1) * 20 + (mr + kx + 1);
      bf16x8 a = *(const bf16x8*)(smem + pos * 144 + h * 64 + kg * 16);
      bf16x8 bb = *(const bf16x8*)(wrow + s * 32);
      cacc = __builtin_amdgcn_mfma_f32_16x16x32_bf16(a, bb, cacc, 0, 0, 0);
    }
    int o = ot * 16 + mr;
    float bias = 0.f;
    if (o < 18) bias = b_off[o];
    else if (o < 27) bias = b_mask[o - 18];
    bool is_mask = (o >= 18) && (o < 27);
#pragma unroll
    for (int r = 0; r < 4; ++r) {
      float v = cacc[r] + bias;
      float sg = 1.f / (1.f + expf(-v));
      float res = is_mask ? sg : v;
      offt[(pr * 16 + kg * 4 + r) * 44 + o] = res;   // transposed store
    }
  }
  __syncthreads();

  // ---- Phase C1-lite: OOB-of-halo scan -> fixup list only ----
#pragma unroll
  for (int pass = 0; pass < 2; ++pass) {
    int tau = tid + pass * 256;
    if (tau < 288) {
      int p = tau / 9;
      int k = tau - p * 9;
      const float* op = offt + p * 44;
      float dy = op[2 * k];
      float dx = op[2 * k + 1];
      float m = op[18 + k];
      int yy_o = y + (p >> 4);
      int xx_o = x0 + (p & 15);
      float py = (float)(yy_o + k / 3 - 1) + dy;
      float pxf = (float)(xx_o + k % 3 - 1) + dx;
      float fy = floorf(py), fx = floorf(pxf);
      int y0i = (int)fy, x0i = (int)fx;
      float wy1 = py - fy, wx1 = pxf - fx;
      float wyv[2] = {1.f - wy1, wy1};
      float wxv[2] = {1.f - wx1, wx1};
#pragma unroll
      for (int ry = 0; ry < 2; ++ry) {
#pragma unroll
        for (int rx = 0; rx < 2; ++rx) {
          int yiq = y0i + ry;
          int xiq = x0i + rx;
          bool valid = ((unsigned)yiq < (unsigned)HH) && ((unsigned)xiq < (unsigned)WW);
          int rr = yiq - (y - 2);
          int jj = xiq - (x0 - 2);
          bool inh = ((unsigned)rr < 6u) && ((unsigned)jj < 20u);
          if (valid && !inh) {
            float w = wyv[ry] * wxv[rx] * m;
            if (w != 0.f) {
              int slot = atomicAdd((int*)(smem + FB_OFF), 1);
              if (slot < FB_MAX) {
                *(uint4*)(smem + FB_OFF + 16 + slot * 16) =
                    make_uint4((uint32)p | ((uint32)k << 8),
                               (uint32)(yiq * WW + xiq),
                               __builtin_bit_cast(uint32, w), 0u);
              }
            }
          }
        }
      }
    }
  }
  __syncthreads();

  // ---- Phase G: register-addressed gather + MFMA ----
  f32x4 acc0 = {0.f, 0.f, 0.f, 0.f}, acc1 = acc0, acc2 = acc0, acc3 = acc0;
  int fbn = min(*(const int*)(smem + FB_OFF), FB_MAX);
  fbn = __builtin_amdgcn_readfirstlane(fbn);
  int kh = wave & 1;
  int px = pr * 16 + mr;
  int cb = kh * 64 + kg * 16;                  // this lane's 8-channel bytes
  const ushort_t* wbase = wbf + (size_t)mr * 576 + kh * 32 + kg * 8;
  {
    // load this pixel's 27 offset/mask values once (broadcast across kg/kh)
    f32x4 ofr[7];
    const float* offp = offt + px * 44;
#pragma unroll
    for (int i = 0; i < 7; ++i) ofr[i] = *(const f32x4*)(offp + i * 4);

    int ybase = y + pr;          // output pixel row
    int xbase = x0 + mr;         // output pixel col
    int ybm2 = y - 2, xbm2 = x0 - 2;

    int4 aA, aB;
    f32x4 wA, wB;
    uint4 dA_0, dA_1, dA_2, dA_3, dB_0, dB_1, dB_2, dB_3;

#define AW(S, T) {                                                            \
    float dy_ = ofr[(2*(T))>>2][(2*(T))&3];                                   \
    float dx_ = ofr[(2*(T)+1)>>2][(2*(T)+1)&3];                               \
    float mm_ = ofr[(18+(T))>>2][(18+(T))&3];                                 \
    float py_ = (float)(ybase + (T)/3 - 1) + dy_;                             \
    float pxx_ = (float)(xbase + (T)%3 - 1) + dx_;                            \
    float fy_ = floorf(py_), fx_ = floorf(pxx_);                              \
    float wy1_ = py_ - fy_, wx1_ = pxx_ - fx_;                                \
    float wy0_ = 1.f - wy1_, wx0_ = 1.f - wx1_;                               \
    int rr_ = (int)fy_ - ybm2, jj_ = (int)fx_ - xbm2;                         \
    a##S.x = haddr(rr_,     jj_,     cb);                                     \
    a##S.y = haddr(rr_,     jj_ + 1, cb);                                     \
    a##S.z = haddr(rr_ + 1, jj_,     cb);                                     \
    a##S.w = haddr(rr_ + 1, jj_ + 1, cb);                                     \
    w##S[0] = hwt(rr_,     jj_,     wy0_ * wx0_, mm_);                        \
    w##S[1] = hwt(rr_,     jj_ + 1, wy0_ * wx1_, mm_);                        \
    w##S[2] = hwt(rr_ + 1, jj_,     wy1_ * wx0_, mm_);                        \
    w##S[3] = hwt(rr_ + 1, jj_ + 1, wy1_ * wx1_, mm_); }
#define LD(S) {                                                               \
    d##S##_0 = *(const uint4*)(smem + a##S.x);                                \
    d##S##_1 = *(const uint4*)(smem + a##S.y);                                \
    d##S##_2 = *(const uint4*)(smem + a##S.z);                                \
    d##S##_3 = *(const uint4*)(smem + a##S.w); }
#define GS(S, T) {                                                            \
    float fw0 = w##S[0], fw1 = w##S[1], fw2 = w##S[2], fw3 = w##S[3];         \
    float s0 = fw0 * bflo(d##S##_0.x), s1 = fw0 * bfhi(d##S##_0.x);           \
    float s2 = fw0 * bflo(d##S##_0.y), s3 = fw0 * bfhi(d##S##_0.y);           \
    float s4 = fw0 * bflo(d##S##_0.z), s5 = fw0 * bfhi(d##S##_0.z);           \
    float s6 = fw0 * bflo(d##S##_0.w), s7 = fw0 * bfhi(d##S##_0.w);           \
    s0 += fw1 * bflo(d##S##_1.x); s1 += fw1 * bfhi(d##S##_1.x);               \
    s2 += fw1 * bflo(d##S##_1.y); s3 += fw1 * bfhi(d##S##_1.y);               \
    s4 += fw1 * bflo(d##S##_1.z); s5 += fw1 * bfhi(d##S##_1.z);               \
    s6 += fw1 * bflo(d##S##_1.w); s7 += fw1 * bfhi(d##S##_1.w);               \
    s0 += fw2 * bflo(d##S##_2.x); s1 += fw2 * bfhi(d##S##_2.x);               \
    s2 += fw2 * bflo(d##S##_2.y); s3 += fw2 * bfhi(d##S##_2.y);               \
    s4 += fw2 * bflo(d##S##_2.z); s5 += fw2 * bfhi(d##S##_2.z);               \
    s6 += fw2 * bflo(d##S##_2.w); s7 += fw2 * bfhi(d##S##_2.w);               \
    s0 += fw3 * bflo(d##S##_3.x); s1 += fw3 * bfhi(d##S##_3.x);               \
    s2 += fw3 * bflo(d##S##_3.y); s3 += fw3 * bfhi(d##S##_3.y);               \
    s4 += fw3 * bflo(d##S##_3.z); s5 += fw3 * bfhi(d##S##_3.z);               \
    s6 += fw3 * bflo(d##S##_3.w); s7 += fw3 * bfhi(d##S##_3.w);               \
    uint32 p0 = __builtin_amdgcn_perm(__builtin_bit_cast(uint32, s1) + 0x8000u, \
                                      __builtin_bit_cast(uint32, s0) + 0x8000u, \
                                      0x07060302u);                           \
    uint32 p1 = __builtin_amdgcn_perm(__builtin_bit_cast(uint32, s3) + 0x8000u, \
                                      __builtin_bit_cast(uint32, s2) + 0x8000u, \
                                      0x07060302u);                           \
    uint32 p2 = __builtin_amdgcn_perm(__builtin_bit_cast(uint32, s5) + 0x8000u, \
                                      __builtin_bit_cast(uint32, s4) + 0x8000u, \
                                      0x07060302u);                           \
    uint32 p3 = __builtin_amdgcn_perm(__builtin_bit_cast(uint32, s7) + 0x8000u, \
                                      __builtin_bit_cast(uint32, s6) + 0x8000u, \
                                      0x07060302u);                           \
    bf16x8 afrag = __builtin_bit_cast(bf16x8, make_uint4(p0, p1, p2, p3));    \
    const ushort_t* wp = wbase + (T) * 64;                                    \
    acc0 = __builtin_amdgcn_mfma_f32_16x16x32_bf16(afrag, *(const bf16x8*)(wp), acc0, 0, 0, 0); \
    acc1 = __builtin_amdgcn_mfma_f32_16x16x32_bf16(afrag, *(const bf16x8*)(wp + 9216), acc1, 0, 0, 0); \
    acc2 = __builtin_amdgcn_mfma_f32_16x16x32_bf16(afrag, *(const bf16x8*)(wp + 18432), acc2, 0, 0, 0); \
    acc3 = __builtin_amdgcn_mfma_f32_16x16x32_bf16(afrag, *(const bf16x8*)(wp + 27648), acc3, 0, 0, 0); }

    AW(A, 0) LD(A)
    AW(B, 1) LD(B)
    GS(A, 0) AW(A, 2) LD(A)
    GS(B, 1) AW(B, 3) LD(B)
    GS(A, 2) AW(A, 4) LD(A)
    GS(B, 3) AW(B, 5) LD(B)
    GS(A, 4) AW(A, 6) LD(A)
    GS(B, 5) AW(B, 7) LD(B)
    GS(A, 6) AW(A, 8) LD(A)
    GS(B, 7)
    GS(A, 8)
#undef AW
#undef LD
#undef GS
  }

  // ---- rare exact fixup (post-loop, wave-uniform) ----
  if (fbn) {
    for (int e = 0; e < fbn; ++e) {
      uint4 ent = *(const uint4*)(smem + FB_OFF + 16 + e * 16);
      int fpx = (int)(ent.x & 255u);
      int ft = (int)(ent.x >> 8);
      float fw = (mr == (fpx & 15) && pr == (fpx >> 4))
                     ? __builtin_bit_cast(float, ent.z) : 0.f;
      uint4 d = *(const uint4*)(xb8 + ((size_t)ent.y << 7) + cb);
      float s0 = fw * bflo(d.x), s1 = fw * bfhi(d.x);
      float s2 = fw * bflo(d.y), s3 = fw * bfhi(d.y);
      float s4 = fw * bflo(d.z), s5 = fw * bfhi(d.z);
      float s6 = fw * bflo(d.w), s7 = fw * bfhi(d.w);
      uint32 p0 = __builtin_amdgcn_perm(__builtin_bit_cast(uint32, s1) + 0x8000u,
                                        __builtin_bit_cast(uint32, s0) + 0x8000u,
                                        0x07060302u);
      uint32 p1 = __builtin_amdgcn_perm(__builtin_bit_cast(uint32, s3) + 0x8000u,
                                        __builtin_bit_cast(uint32, s2) + 0x8000u,
                                        0x07060302u);
      uint32 p2 = __builtin_amdgcn_perm(__builtin_bit_cast(uint32, s5) + 0x8000u,
                                        __builtin_bit_cast(uint32, s4) + 0x8000u,
                                        0x07060302u);
      uint32 p3 = __builtin_amdgcn_perm(__builtin_bit_cast(uint32, s7) + 0x8000u,
                                        __builtin_bit_cast(uint32, s6) + 0x8000u,
                                        0x07060302u);
      bf16x8 afrag = __builtin_bit_cast(bf16x8, make_uint4(p0, p1, p2, p3));
      const ushort_t* wp = wbase + ft * 64;
      acc0 = __builtin_amdgcn_mfma_f32_16x16x32_bf16(afrag, *(const bf16x8*)(wp), acc0, 0, 0, 0);
      acc1 = __builtin_amdgcn_mfma_f32_16x16x32_bf16(afrag, *(const bf16x8*)(wp + 9216), acc1, 0, 0, 0);
      acc2 = __builtin_amdgcn_mfma_f32_16x16x32_bf16(afrag, *(const bf16x8*)(wp + 18432), acc2, 0, 0, 0);
      acc3 = __builtin_amdgcn_mfma_f32_16x16x32_bf16(afrag, *(const bf16x8*)(wp + 27648), acc3, 0, 0, 0);
    }
  }

  // ---- Phase R: 2-way reduce (kh pairs) over dead halo; kh=0 stores ----
  __syncthreads();                 // all halo/offt reads done before overlay
  {
    if (kh == 1) {
      red[(pr * 4 + 0) * 64 + lane] = acc0;
      red[(pr * 4 + 1) * 64 + lane] = acc1;
      red[(pr * 4 + 2) * 64 + lane] = acc2;
      red[(pr * 4 + 3) * 64 + lane] = acc3;
    }
    __syncthreads();
    if (kh == 0) {
      f32x4 v0 = acc0 + red[(pr * 4 + 0) * 64 + lane];
      f32x4 v1 = acc1 + red[(pr * 4 + 1) * 64 + lane];
      f32x4 v2 = acc2 + red[(pr * 4 + 2) * 64 + lane];
      f32x4 v3 = acc3 + red[(pr * 4 + 3) * 64 + lane];
      size_t rowoff = (size_t)(y + pr) * WW + x0 + kg * 4;
      *(f32x4*)(out + (size_t)(b * 64 + 0 * 16 + mr) * HWHW + rowoff) = v0;
      *(f32x4*)(out + (size_t)(b * 64 + 1 * 16 + mr) * HWHW + rowoff) = v1;
      *(f32x4*)(out + (size_t)(b * 64 + 2 * 16 + mr) * HWHW + rowoff) = v2;
      *(f32x4*)(out + (size_t)(b * 64 + 3 * 16 + mr) * HWHW + rowoff) = v3;
    }
  }
}

extern "C" void kernel_launch(void* const* d_in, const int* in_sizes, int n_in,
                              void* d_out, int out_size, void* d_ws, size_t ws_size,
                              hipStream_t stream) {
  const float* x = (const float*)d_in[0];
  const float* w_off = (const float*)d_in[1];
  const float* b_off = (const float*)d_in[2];
  const float* w_mask = (const float*)d_in[3];
  const float* b_mask = (const float*)d_in[4];
  const float* w_dcn = (const float*)d_in[5];
  float* out = (float*)d_out;

  char* ws = (char*)d_ws;
  ushort_t* xtbf = (ushort_t*)ws;                         // 16,777,216 B
  ushort_t* wbf = (ushort_t*)(ws + 16777216);             //     73,728 B
  ushort_t* w_om = (ushort_t*)(ws + 16777216 + 73728);    //     36,864 B

  hipLaunchKernelGGL(k_transpose, dim3(2048), dim3(256), 0, stream, x, xtbf);
  hipLaunchKernelGGL(k_wcast, dim3(216), dim3(256), 0, stream, w_dcn, w_off, w_mask,
                     wbf, w_om);
  hipLaunchKernelGGL(k_deform, dim3(4096), dim3(256), 0, stream, xtbf, w_om,
                     b_off, b_mask, wbf, out);
}